// Round 1
// baseline (448.694 us; speedup 1.0000x reference)
//
#include <hip/hip_runtime.h>
#include <math.h>

#define B_TOT 3072
#define PIX   12288   // 64*64*3 elements per batch image

// ---------------------------------------------------------------------------
// Kernel A: per batch b, compute v1,v2 (6 dot products of length 12288),
// L1-normalize, G = V^T V (2x2), Ginv, and store M = Ginv * V^T (2x3) as
// doubles into workspace. fp64 accumulation: Ginv can amplify dot-product
// error by ~1/det (~140x observed), doubles make our V essentially exact.
// ---------------------------------------------------------------------------
__global__ __launch_bounds__(256) void compute_M_kernel(
    const float* __restrict__ x, const float* __restrict__ w1,
    const float* __restrict__ b1, const float* __restrict__ w2,
    const float* __restrict__ b2, double* __restrict__ Mout) {
  const int b = blockIdx.x;
  const float* xb = x + (size_t)b * PIX;
  double s[6] = {0, 0, 0, 0, 0, 0};
  for (int i = threadIdx.x; i < PIX; i += 256) {
    double xv = (double)xb[i];
    int i3 = i * 3;   // w layout: (h,w,c,f) -> flat (hw*3+c)*3+f = i*3+f
    s[0] += xv * (double)w1[i3 + 0];
    s[1] += xv * (double)w1[i3 + 1];
    s[2] += xv * (double)w1[i3 + 2];
    s[3] += xv * (double)w2[i3 + 0];
    s[4] += xv * (double)w2[i3 + 1];
    s[5] += xv * (double)w2[i3 + 2];
  }
  // wave64 butterfly reduce, then cross-wave via LDS
  #pragma unroll
  for (int j = 0; j < 6; ++j) {
    #pragma unroll
    for (int off = 32; off > 0; off >>= 1)
      s[j] += __shfl_down(s[j], off, 64);
  }
  __shared__ double wred[4][6];
  const int wave = threadIdx.x >> 6, lane = threadIdx.x & 63;
  if (lane == 0) {
    #pragma unroll
    for (int j = 0; j < 6; ++j) wred[wave][j] = s[j];
  }
  __syncthreads();
  if (threadIdx.x == 0) {
    double v[3][2];   // v[c][k]: c = output-feature index (3), k = which conv
    for (int c = 0; c < 3; ++c) {
      double a1 = wred[0][c] + wred[1][c] + wred[2][c] + wred[3][c];
      double a2 = wred[0][3 + c] + wred[1][3 + c] + wred[2][3 + c] + wred[3][3 + c];
      v[c][0] = a1 + (double)b1[c];
      v[c][1] = a2 + (double)b2[c];
    }
    // per-column L1 normalization: V[:,k] /= (1e-6 + sum_c |V[c,k]|)
    for (int k = 0; k < 2; ++k) {
      double l1 = 1e-6 + fabs(v[0][k]) + fabs(v[1][k]) + fabs(v[2][k]);
      for (int c = 0; c < 3; ++c) v[c][k] /= l1;
    }
    double G00 = 0, G01 = 0, G10 = 0, G11 = 0;
    for (int c = 0; c < 3; ++c) {
      G00 += v[c][0] * v[c][0];
      G01 += v[c][0] * v[c][1];
      G10 += v[c][1] * v[c][0];
      G11 += v[c][1] * v[c][1];
    }
    double det = G00 * G11 - G01 * G10;
    double i00 = G11 / det, i01 = -G01 / det, i10 = -G10 / det, i11 = G00 / det;
    // M[k][c] = sum_j Ginv[k][j] * V[c][j]
    double* Mo = Mout + (size_t)b * 6;
    for (int c = 0; c < 3; ++c) {
      Mo[0 * 3 + c] = i00 * v[c][0] + i01 * v[c][1];
      Mo[1 * 3 + c] = i10 * v[c][0] + i11 * v[c][1];
    }
  }
}

// ---------------------------------------------------------------------------
// Kernel B: one block per output image b2 (2048 blocks).
//   z flat index m = b2*12288 + m_local maps to z[b,k,n]:
//     b = m>>13, n = (m&8191)>>1, k = m&1;  z = M[b][k] . x[b,n,0..2]
//   Phase 1: rec into LDS (layout h*192 + w*3 + c) + store channels 0..2.
//   Phase 2: Hilbert along h = 64-tap circular conv, gi[d]=(1/32)cot(pi d/64)
//   for odd d. 192 threads each hold one column (64 floats) in REGISTERS
//   (fully unrolled, static indices) + 32 tap coeffs in registers — avoids
//   LDS-throughput-bound broadcast reads.
// ---------------------------------------------------------------------------
__global__ __launch_bounds__(256) void z_hilbert_kernel(
    const float* __restrict__ x, const double* __restrict__ M,
    float* __restrict__ out) {
  const int b2 = blockIdx.x;
  __shared__ float rec[PIX];      // 48 KB
  __shared__ float Ms[12];        // M for the (at most) 2 source batches
  const size_t zbase = (size_t)b2 * PIX;
  const int b_lo = (int)(zbase >> 13);
  if (threadIdx.x < 12) {
    int bb = b_lo + (int)(threadIdx.x / 6);
    float mv = 0.f;
    if (bb < B_TOT) mv = (float)M[(size_t)bb * 6 + (threadIdx.x % 6)];
    Ms[threadIdx.x] = mv;
  }
  __syncthreads();
  float* outb = out + (size_t)b2 * 24576;   // (64,64,6) per image

  // Phase 1: one (b,n) pair per iteration -> both k values share the x load.
  for (int j = threadIdx.x; j < PIX / 2; j += 256) {
    int ml = j << 1;                      // m_local (k=0 element)
    size_t m = zbase + (size_t)ml;
    int b = (int)(m >> 13);
    int n = (int)((m & 8191) >> 1);
    int wb = (b - b_lo) * 6;
    const float* xp = x + (size_t)b * PIX + n * 3;
    float x0 = xp[0], x1 = xp[1], x2 = xp[2];
    float r0 = Ms[wb + 0] * x0 + Ms[wb + 1] * x1 + Ms[wb + 2] * x2;
    float r1 = Ms[wb + 3] * x0 + Ms[wb + 4] * x1 + Ms[wb + 5] * x2;
    rec[ml] = r0;
    rec[ml + 1] = r1;
    int h0 = ml / 192, rem0 = ml % 192;
    outb[h0 * 384 + (rem0 / 3) * 6 + (rem0 % 3)] = r0;
    int ml1 = ml + 1;
    int h1 = ml1 / 192, rem1 = ml1 % 192;
    outb[h1 * 384 + (rem1 / 3) * 6 + (rem1 % 3)] = r1;
  }
  __syncthreads();

  // Phase 2: Hilbert per column, inputs + taps in registers.
  if (threadIdx.x < 192) {
    const int col = threadIdx.x;
    const int w = col / 3, c = col % 3;
    float gc[32];
    #pragma unroll
    for (int jj = 0; jj < 32; ++jj) {
      float ang = 3.14159265358979323846f * (float)(2 * jj + 1) / 64.0f;
      gc[jj] = 0.03125f * cosf(ang) / sinf(ang);   // (1/32)cot(pi d/64), odd d
    }
    float v[64];
    #pragma unroll
    for (int h = 0; h < 64; ++h) v[h] = rec[h * 192 + col];
    #pragma unroll
    for (int h = 0; h < 64; ++h) {
      float acc = 0.f;
      #pragma unroll
      for (int jj = 0; jj < 32; ++jj) {
        int d = 2 * jj + 1;
        acc += gc[jj] * v[(h - d) & 63];
      }
      outb[h * 384 + w * 6 + c + 3] = acc;
    }
  }
}

extern "C" void kernel_launch(void* const* d_in, const int* in_sizes, int n_in,
                              void* d_out, int out_size, void* d_ws, size_t ws_size,
                              hipStream_t stream) {
  const float* x  = (const float*)d_in[0];   // (3072,64,64,3)
  const float* w1 = (const float*)d_in[1];   // (64,64,3,3)
  const float* b1 = (const float*)d_in[2];   // (3,)
  const float* w2 = (const float*)d_in[3];   // (64,64,3,3)
  const float* b2 = (const float*)d_in[4];   // (3,)
  float* out = (float*)d_out;                // (2048,64,64,6)
  double* M = (double*)d_ws;                 // 3072*6 doubles = 147456 B

  compute_M_kernel<<<B_TOT, 256, 0, stream>>>(x, w1, b1, w2, b2, M);
  z_hilbert_kernel<<<2048, 256, 0, stream>>>(x, M, out);
}

// Round 2
// 397.233 us; speedup vs baseline: 1.1295x; 1.1295x over previous
//
#include <hip/hip_runtime.h>
#include <math.h>

#define B_TOT 3072
#define PIX   12288   // 64*64*3 elements per batch image

// ---------------------------------------------------------------------------
// Kernel A: per batch b, compute v1,v2 (6 dot products of length 12288),
// L1-normalize, G = V^T V (2x2), Ginv, store M = Ginv * V^T (2x3) as floats.
// fp32 per-thread partials (48 tiny terms each), fp64 cross-lane reduction +
// 2x2 inversion: dot error ~1e-6 rel, amplified by kappa(G) stays << 2.82
// threshold (measured algorithmic floor is 0.5).
// float4 loads: x is 3072 float4/batch; w groups of 12 floats = 3 float4
// (16B-aligned since element base i = 4*i4 -> byte offset 48*i4).
// ---------------------------------------------------------------------------
__global__ __launch_bounds__(256) void compute_M_kernel(
    const float* __restrict__ x, const float* __restrict__ w1,
    const float* __restrict__ b1, const float* __restrict__ w2,
    const float* __restrict__ b2, float* __restrict__ Mout) {
  const int b = blockIdx.x;
  const float4* xb4 = (const float4*)(x + (size_t)b * PIX);
  const float4* w14 = (const float4*)w1;
  const float4* w24 = (const float4*)w2;
  float s[6] = {0, 0, 0, 0, 0, 0};
  for (int i4 = threadIdx.x; i4 < PIX / 4; i4 += 256) {
    float4 xv = xb4[i4];
    float4 a0 = w14[i4 * 3 + 0], a1 = w14[i4 * 3 + 1], a2 = w14[i4 * 3 + 2];
    float4 c0 = w24[i4 * 3 + 0], c1 = w24[i4 * 3 + 1], c2 = w24[i4 * 3 + 2];
    // group layout g[e*3+f], e=element 0..3, f=feature 0..2
    s[0] += xv.x * a0.x + xv.y * a0.w + xv.z * a1.z + xv.w * a2.y;
    s[1] += xv.x * a0.y + xv.y * a1.x + xv.z * a1.w + xv.w * a2.z;
    s[2] += xv.x * a0.z + xv.y * a1.y + xv.z * a2.x + xv.w * a2.w;
    s[3] += xv.x * c0.x + xv.y * c0.w + xv.z * c1.z + xv.w * c2.y;
    s[4] += xv.x * c0.y + xv.y * c1.x + xv.z * c1.w + xv.w * c2.z;
    s[5] += xv.x * c0.z + xv.y * c1.y + xv.z * c2.x + xv.w * c2.w;
  }
  double sd[6];
  #pragma unroll
  for (int j = 0; j < 6; ++j) {
    sd[j] = (double)s[j];
    #pragma unroll
    for (int off = 32; off > 0; off >>= 1)
      sd[j] += __shfl_down(sd[j], off, 64);
  }
  __shared__ double wred[4][6];
  const int wave = threadIdx.x >> 6, lane = threadIdx.x & 63;
  if (lane == 0) {
    #pragma unroll
    for (int j = 0; j < 6; ++j) wred[wave][j] = sd[j];
  }
  __syncthreads();
  if (threadIdx.x == 0) {
    double v[3][2];   // v[c][k]
    for (int c = 0; c < 3; ++c) {
      v[c][0] = wred[0][c] + wred[1][c] + wred[2][c] + wred[3][c] + (double)b1[c];
      v[c][1] = wred[0][3 + c] + wred[1][3 + c] + wred[2][3 + c] + wred[3][3 + c] + (double)b2[c];
    }
    for (int k = 0; k < 2; ++k) {
      double l1 = 1e-6 + fabs(v[0][k]) + fabs(v[1][k]) + fabs(v[2][k]);
      for (int c = 0; c < 3; ++c) v[c][k] /= l1;
    }
    double G00 = 0, G01 = 0, G11 = 0;
    for (int c = 0; c < 3; ++c) {
      G00 += v[c][0] * v[c][0];
      G01 += v[c][0] * v[c][1];
      G11 += v[c][1] * v[c][1];
    }
    double det = G00 * G11 - G01 * G01;
    double i00 = G11 / det, i01 = -G01 / det, i11 = G00 / det;
    float* Mo = Mout + (size_t)b * 6;
    for (int c = 0; c < 3; ++c) {
      Mo[0 * 3 + c] = (float)(i00 * v[c][0] + i01 * v[c][1]);
      Mo[1 * 3 + c] = (float)(i01 * v[c][0] + i11 * v[c][1]);
    }
  }
}

// ---------------------------------------------------------------------------
// Kernel B: one block (192 threads) per output image b2 (2048 blocks).
//   z flat m = b2*12288 + ml maps to (b = m>>13, n = (m&8191)>>1, k = m&1);
//   z = M[b][k] . x[b,n,0..2].
//   Phase 1: rec into LDS only (float2 stores), layout h*192 + w*3 + c.
//   Phase 2: each thread owns one column (w,c): pulls 64 rows into registers,
//   computes Hilbert (antisymmetric 16-tap form: g[64-d] = -g[d]) and stores
//   BOTH rec (ch c) and hilbert (ch c+3) interleaved per h, so every 64B line
//   of out becomes fully dirty within a few cycles -> no partial-line
//   writeback amplification (R1 showed WRITE_SIZE = 1.96x ideal from the
//   split-phase write pattern).
// ---------------------------------------------------------------------------
__global__ __launch_bounds__(192) void z_hilbert_kernel(
    const float* __restrict__ x, const float* __restrict__ M,
    float* __restrict__ out) {
  const int b2 = blockIdx.x;
  __shared__ float rec[PIX];      // 48 KB
  __shared__ float Ms[12];        // M for the (at most) 2 source batches
  const size_t zbase = (size_t)b2 * PIX;
  const int b_lo = (int)(zbase >> 13);
  if (threadIdx.x < 12) {
    int bb = b_lo + (int)(threadIdx.x / 6);
    float mv = 0.f;
    if (bb < B_TOT) mv = M[(size_t)bb * 6 + (threadIdx.x % 6)];
    Ms[threadIdx.x] = mv;
  }
  __syncthreads();
  float* outb = out + (size_t)b2 * 24576;   // (64,64,6) per image

  // Phase 1: one (b,n) pair per iteration; both k share the 3 x-loads.
  for (int j = threadIdx.x; j < PIX / 2; j += 192) {
    int ml = j << 1;
    size_t m = zbase + (size_t)ml;
    int b = (int)(m >> 13);
    int n = (int)((m & 8191) >> 1);
    int wb = (b - b_lo) * 6;
    const float* xp = x + (size_t)b * PIX + n * 3;
    float x0 = xp[0], x1 = xp[1], x2 = xp[2];
    float r0 = Ms[wb + 0] * x0 + Ms[wb + 1] * x1 + Ms[wb + 2] * x2;
    float r1 = Ms[wb + 3] * x0 + Ms[wb + 4] * x1 + Ms[wb + 5] * x2;
    float2 rr; rr.x = r0; rr.y = r1;
    ((float2*)rec)[j] = rr;
  }
  __syncthreads();

  // Phase 2: Hilbert per column; column + taps in registers.
  {
    const int col = threadIdx.x;       // 0..191
    const int w = col / 3, c = col % 3;
    float gc[16];
    #pragma unroll
    for (int jj = 0; jj < 16; ++jj) {
      float ang = 3.14159265358979323846f * (float)(2 * jj + 1) / 64.0f;
      gc[jj] = 0.03125f * cosf(ang) / sinf(ang);   // (1/32)cot(pi d/64), odd d
    }
    float v[64];
    #pragma unroll
    for (int h = 0; h < 64; ++h) v[h] = rec[h * 192 + col];
    float* oc = outb + w * 6 + c;
    #pragma unroll
    for (int h = 0; h < 64; ++h) {
      float acc = 0.f;
      #pragma unroll
      for (int jj = 0; jj < 16; ++jj) {
        int d = 2 * jj + 1;
        acc += gc[jj] * (v[(h - d) & 63] - v[(h + d) & 63]);
      }
      oc[h * 384 + 0] = v[h];
      oc[h * 384 + 3] = acc;
    }
  }
}

extern "C" void kernel_launch(void* const* d_in, const int* in_sizes, int n_in,
                              void* d_out, int out_size, void* d_ws, size_t ws_size,
                              hipStream_t stream) {
  const float* x  = (const float*)d_in[0];   // (3072,64,64,3)
  const float* w1 = (const float*)d_in[1];   // (64,64,3,3)
  const float* b1 = (const float*)d_in[2];   // (3,)
  const float* w2 = (const float*)d_in[3];   // (64,64,3,3)
  const float* b2 = (const float*)d_in[4];   // (3,)
  float* out = (float*)d_out;                // (2048,64,64,6)
  float* M = (float*)d_ws;                   // 3072*6 floats

  compute_M_kernel<<<B_TOT, 256, 0, stream>>>(x, w1, b1, w2, b2, M);
  z_hilbert_kernel<<<2048, 192, 0, stream>>>(x, M, out);
}

// Round 3
// 373.905 us; speedup vs baseline: 1.2000x; 1.0624x over previous
//
#include <hip/hip_runtime.h>
#include <math.h>

#define B_TOT 3072
#define PIX   12288   // 64*64*3 elements per batch image

typedef float v2f __attribute__((ext_vector_type(2)));

// ---------------------------------------------------------------------------
// Kernel A: per batch b, compute v1,v2 (6 dot products of length 12288),
// L1-normalize, G = V^T V (2x2), Ginv, store M = Ginv * V^T (2x3) as floats.
// fp32 per-thread partials + fp32 wave shuffles; fp64 only for the final
// cross-wave combine and 2x2 inversion (kappa(G) amplification). Measured
// algorithmic floor: absmax 0.5 vs 2.82 threshold.
// ---------------------------------------------------------------------------
__global__ __launch_bounds__(256) void compute_M_kernel(
    const float* __restrict__ x, const float* __restrict__ w1,
    const float* __restrict__ b1, const float* __restrict__ w2,
    const float* __restrict__ b2, float* __restrict__ Mout) {
  const int b = blockIdx.x;
  const float4* xb4 = (const float4*)(x + (size_t)b * PIX);
  const float4* w14 = (const float4*)w1;
  const float4* w24 = (const float4*)w2;
  float s[6] = {0, 0, 0, 0, 0, 0};
  #pragma unroll 4
  for (int i4 = threadIdx.x; i4 < PIX / 4; i4 += 256) {
    float4 xv = xb4[i4];
    float4 a0 = w14[i4 * 3 + 0], a1 = w14[i4 * 3 + 1], a2 = w14[i4 * 3 + 2];
    float4 c0 = w24[i4 * 3 + 0], c1 = w24[i4 * 3 + 1], c2 = w24[i4 * 3 + 2];
    // group layout g[e*3+f], e=element 0..3, f=feature 0..2
    s[0] += xv.x * a0.x + xv.y * a0.w + xv.z * a1.z + xv.w * a2.y;
    s[1] += xv.x * a0.y + xv.y * a1.x + xv.z * a1.w + xv.w * a2.z;
    s[2] += xv.x * a0.z + xv.y * a1.y + xv.z * a2.x + xv.w * a2.w;
    s[3] += xv.x * c0.x + xv.y * c0.w + xv.z * c1.z + xv.w * c2.y;
    s[4] += xv.x * c0.y + xv.y * c1.x + xv.z * c1.w + xv.w * c2.z;
    s[5] += xv.x * c0.z + xv.y * c1.y + xv.z * c2.x + xv.w * c2.w;
  }
  #pragma unroll
  for (int j = 0; j < 6; ++j) {
    #pragma unroll
    for (int off = 32; off > 0; off >>= 1)
      s[j] += __shfl_down(s[j], off, 64);
  }
  __shared__ float wred[4][6];
  const int wave = threadIdx.x >> 6, lane = threadIdx.x & 63;
  if (lane == 0) {
    #pragma unroll
    for (int j = 0; j < 6; ++j) wred[wave][j] = s[j];
  }
  __syncthreads();
  if (threadIdx.x == 0) {
    double v[3][2];   // v[c][k]
    for (int c = 0; c < 3; ++c) {
      v[c][0] = (double)wred[0][c] + (double)wred[1][c] + (double)wred[2][c] +
                (double)wred[3][c] + (double)b1[c];
      v[c][1] = (double)wred[0][3 + c] + (double)wred[1][3 + c] +
                (double)wred[2][3 + c] + (double)wred[3][3 + c] + (double)b2[c];
    }
    for (int k = 0; k < 2; ++k) {
      double l1 = 1e-6 + fabs(v[0][k]) + fabs(v[1][k]) + fabs(v[2][k]);
      for (int c = 0; c < 3; ++c) v[c][k] /= l1;
    }
    double G00 = 0, G01 = 0, G11 = 0;
    for (int c = 0; c < 3; ++c) {
      G00 += v[c][0] * v[c][0];
      G01 += v[c][0] * v[c][1];
      G11 += v[c][1] * v[c][1];
    }
    double det = G00 * G11 - G01 * G01;
    double i00 = G11 / det, i01 = -G01 / det, i11 = G00 / det;
    float* Mo = Mout + (size_t)b * 6;
    for (int c = 0; c < 3; ++c) {
      Mo[0 * 3 + c] = (float)(i00 * v[c][0] + i01 * v[c][1]);
      Mo[1 * 3 + c] = (float)(i01 * v[c][0] + i11 * v[c][1]);
    }
  }
}

// ---------------------------------------------------------------------------
// Kernel B: one block (256 threads) per output image b2 (2048 blocks).
//   z flat m = b2*12288 + ml -> (b = m>>13, n = (m&8191)>>1, k = m&1);
//   z = M[b][k] . x[b,n,0..2].
//   Phase 1: groups of 4 pixels (8 z) per thread-iter: 3 float4 x-loads +
//   2 float4 LDS writes. Group base n0 % 4 == 0 (16B aligned) and a group
//   never straddles a batch boundary (8192 % 8 == 0).
//   Phase 2: 48 active lanes/wave own one column (w = wave*16 + lane/3,
//   c = lane%3) so the group-of-3 lane transpose stays inside one wave.
//   Column (64 rows) + 16 antisymmetric taps live in registers. Per h:
//   2 shuffles re-pack (rec,hil) of the 3-lane group into contiguous
//   float2 per lane -> one nontemporal dwordx2 store; a wave writes 384 B
//   contiguous, every 64B line fully dirty immediately (no partial-line
//   RMW; R1 showed 1.96x write amplification from split-channel writes).
// ---------------------------------------------------------------------------
__global__ __launch_bounds__(256) void z_hilbert_kernel(
    const float* __restrict__ x, const float* __restrict__ M,
    float* __restrict__ out) {
  const int b2 = blockIdx.x;
  __shared__ __align__(16) float rec[PIX];   // 48 KB
  __shared__ float Ms[12];
  const size_t zbase = (size_t)b2 * PIX;
  const int b_lo = (int)(zbase >> 13);
  if (threadIdx.x < 12) {
    int bb = b_lo + (int)(threadIdx.x / 6);
    float mv = 0.f;
    if (bb < B_TOT) mv = M[(size_t)bb * 6 + (threadIdx.x % 6)];
    Ms[threadIdx.x] = mv;
  }
  __syncthreads();
  float* outb = out + (size_t)b2 * 24576;   // (64,64,6) per image

  // Phase 1: 1536 groups of 4 pixels; 6 iterations per thread.
  for (int g = threadIdx.x; g < PIX / 8; g += 256) {
    int ml = g << 3;
    size_t m = zbase + (size_t)ml;
    int b = (int)(m >> 13);
    int n0 = (int)((m & 8191) >> 1);        // n0 % 4 == 0
    int wb = (b - b_lo) * 6;
    float m00 = Ms[wb + 0], m01 = Ms[wb + 1], m02 = Ms[wb + 2];
    float m10 = Ms[wb + 3], m11 = Ms[wb + 4], m12 = Ms[wb + 5];
    const float4* xp = (const float4*)(x + (size_t)b * PIX + (size_t)n0 * 3);
    float4 p0 = xp[0], p1 = xp[1], p2 = xp[2];
    float4 o0, o1;
    o0.x = m00 * p0.x + m01 * p0.y + m02 * p0.z;
    o0.y = m10 * p0.x + m11 * p0.y + m12 * p0.z;
    o0.z = m00 * p0.w + m01 * p1.x + m02 * p1.y;
    o0.w = m10 * p0.w + m11 * p1.x + m12 * p1.y;
    o1.x = m00 * p1.z + m01 * p1.w + m02 * p2.x;
    o1.y = m10 * p1.z + m11 * p1.w + m12 * p2.x;
    o1.z = m00 * p2.y + m01 * p2.z + m02 * p2.w;
    o1.w = m10 * p2.y + m11 * p2.z + m12 * p2.w;
    float4* rp = (float4*)&rec[ml];
    rp[0] = o0;
    rp[1] = o1;
  }
  __syncthreads();

  // Phase 2
  const int wave = threadIdx.x >> 6, lane = threadIdx.x & 63;
  if (lane < 48) {
    const int w = wave * 16 + lane / 3;
    const int c = lane % 3;
    const int col = w * 3 + c;
    float gc[16];
    #pragma unroll
    for (int jj = 0; jj < 16; ++jj) {
      float ang = 3.14159265358979323846f * (float)(2 * jj + 1) / 64.0f;
      gc[jj] = 0.03125f * cosf(ang) / sinf(ang);   // (1/32)cot(pi d/64), odd d
    }
    float v[64];
    #pragma unroll
    for (int h = 0; h < 64; ++h) v[h] = rec[h * 192 + col];
    float* oc = outb + w * 6 + c * 2;   // this lane's float2 slot per pixel
    #pragma unroll
    for (int h = 0; h < 64; ++h) {
      float acc = 0.f;
      #pragma unroll
      for (int jj = 0; jj < 16; ++jj) {
        int d = 2 * jj + 1;
        acc += gc[jj] * (v[(h - d) & 63] - v[(h + d) & 63]);
      }
      float r = v[h];
      // lane transpose within group of 3: pixel = [r0,r1,r2,a0,a1,a2]
      float s1 = __shfl(r, lane + 1, 64);    // r of next lane (c+1)
      float s2 = __shfl(acc, lane - 1, 64);  // a of prev lane (c-1)
      v2f st;
      st.x = (c == 0) ? r : ((c == 1) ? s1 : s2);
      st.y = (c == 0) ? s1 : ((c == 1) ? s2 : acc);
      __builtin_nontemporal_store(st, (v2f*)(oc + (size_t)h * 384));
    }
  }
}

extern "C" void kernel_launch(void* const* d_in, const int* in_sizes, int n_in,
                              void* d_out, int out_size, void* d_ws, size_t ws_size,
                              hipStream_t stream) {
  const float* x  = (const float*)d_in[0];   // (3072,64,64,3)
  const float* w1 = (const float*)d_in[1];   // (64,64,3,3)
  const float* b1 = (const float*)d_in[2];   // (3,)
  const float* w2 = (const float*)d_in[3];   // (64,64,3,3)
  const float* b2 = (const float*)d_in[4];   // (3,)
  float* out = (float*)d_out;                // (2048,64,64,6)
  float* M = (float*)d_ws;                   // 3072*6 floats

  compute_M_kernel<<<B_TOT, 256, 0, stream>>>(x, w1, b1, w2, b2, M);
  z_hilbert_kernel<<<2048, 256, 0, stream>>>(x, M, out);
}